// Round 10
// baseline (260.800 us; speedup 1.0000x reference)
//
#include <hip/hip_runtime.h>

typedef _Float16 half8  __attribute__((ext_vector_type(8)));
typedef __fp16   fp16x2 __attribute__((ext_vector_type(2)));
typedef float    f32x16 __attribute__((ext_vector_type(16)));
typedef unsigned uint2v __attribute__((ext_vector_type(2)));

#define NWG     256
#define WGSZ    512
#define CHUNKS  8          // samples per WG = CHUNKS*WGSZ = 4096; grid covers 1048576
// u32 offsets inside static LDS. Mid layers have 9 kk slots (kk=8 = bias row).
#define WFRAG0   0         // W2: 9216 u32
#define WFRAG1   9216      // W3
#define WFRAG2   18432     // W4
#define W1FRAGO  27648     // 1024 u32 (bias folded at k=3)
#define W5FRAGO  28672     // 2048 u32
#define B5O      30720     // b5: 2 f32
#define SMEM_U32 30722     // 122888 B static LDS -> 1 WG/CU

// Fence the instruction scheduler (r9: this removed 1.6GB/dispatch of scratch
// spill by capping load-hoisting scope; VGPR pressure must stay < 128).
#define FENCE() __builtin_amdgcn_sched_barrier(0)

__device__ __forceinline__ unsigned pack_rn(float a, float b) {
  unsigned lo = (unsigned)__builtin_bit_cast(unsigned short, (_Float16)a);
  unsigned hi = (unsigned)__builtin_bit_cast(unsigned short, (_Float16)b);
  return lo | (hi << 16);
}
__device__ __forceinline__ unsigned pack_rtz(float a, float b) {
  fp16x2 h = __builtin_amdgcn_cvt_pkrtz(a, b);
  return __builtin_bit_cast(unsigned, h);
}
// swish = v * rcp(1 + 2^(-v*log2e)) : 3 VALU + 2 trans
__device__ __forceinline__ float sw(float v) {
  float e = __builtin_amdgcn_exp2f(v * -1.44269504089f);
  return v * __builtin_amdgcn_rcpf(1.0f + e);
}
__device__ __forceinline__ half8 ldfrag(const unsigned* p) {
  uint4 u = *reinterpret_cast<const uint4*>(p);
  return __builtin_bit_cast(half8, u);
}
__device__ __forceinline__ half8 mkfrag(unsigned a, unsigned b, unsigned c, unsigned d) {
  uint4 u = make_uint4(a, b, c, d);
  return __builtin_bit_cast(half8, u);
}

__device__ __forceinline__ void pl_swap(unsigned &a, unsigned &b) {
#if __has_builtin(__builtin_amdgcn_permlane32_swap)
  uint2v r = __builtin_amdgcn_permlane32_swap(a, b, false, false);
  a = r.x; b = r.y;
#else
  asm("v_permlane32_swap_b32 %0, %1" : "+v"(a), "+v"(b));
#endif
}

// Regroup packed D-frag (source frag ks) into the two B-frags for kk=2ks, 2ks+1.
__device__ __forceinline__ void build_b(const unsigned (&p)[8], half8 &bf0, half8 &bf1) {
  unsigned a0 = p[0], a2 = p[2];
  unsigned a1 = p[1], a3 = p[3];
  unsigned a4 = p[4], a6 = p[6];
  unsigned a5 = p[5], a7 = p[7];
  pl_swap(a0, a2);
  pl_swap(a1, a3);
  pl_swap(a4, a6);
  pl_swap(a5, a7);
  bf0 = mkfrag(a0, a1, a2, a3);
  bf1 = mkfrag(a4, a5, a6, a7);
}

// One 128x128 layer for 32 samples. bf hoisted (built ONCE, not per quarter:
// r9 rebuilt them 4x = 144 extra pl_swaps/pass), acc[4] = 4 independent MFMA
// chains, bias applied via the kk=8 weight slot (no LDS bias reads).
// Peak live: bf(32) + acc(64) + frags(16, FENCE per kk) ~ 115 < 128.
__device__ __forceinline__ void layer_v2(const unsigned (&pin)[4][8], unsigned (&pout)[4][8],
                                         const unsigned* wb, unsigned bias_w0, int lane) {
  // phase A: build all B-frags; pin dies here
  half8 bf[4][2];
#pragma unroll
  for (int ks = 0; ks < 4; ++ks) build_b(pin[ks], bf[ks][0], bf[ks][1]);
  FENCE();
  // phase B: MFMA over 8 weight kk slots + bias slot
  f32x16 acc[4];
#pragma unroll
  for (int mi = 0; mi < 4; ++mi)
#pragma unroll
    for (int e = 0; e < 16; ++e) acc[mi][e] = 0.f;
#pragma unroll
  for (int kk = 0; kk < 8; ++kk) {
#pragma unroll
    for (int mi = 0; mi < 4; ++mi) {
      half8 a = ldfrag(wb + ((kk*4 + mi)*64 + lane)*4);
      acc[mi] = __builtin_amdgcn_mfma_f32_32x32x16_f16(a, bf[kk>>1][kk&1], acc[mi], 0, 0, 0);
    }
    FENCE();
  }
  {
    half8 bb = mkfrag(bias_w0, 0u, 0u, 0u);  // B[k=128]=1 for every sample col
#pragma unroll
    for (int mi = 0; mi < 4; ++mi) {
      half8 a = ldfrag(wb + ((8*4 + mi)*64 + lane)*4);  // row128 = bias, rest 0
      acc[mi] = __builtin_amdgcn_mfma_f32_32x32x16_f16(a, bb, acc[mi], 0, 0, 0);
    }
  }
  FENCE();
  // phase C: swish + pack
#pragma unroll
  for (int mi = 0; mi < 4; ++mi)
#pragma unroll
    for (int p = 0; p < 8; ++p)
      pout[mi][p] = pack_rtz(sw(acc[mi][2*p]), sw(acc[mi][2*p+1]));
  FENCE();
}

extern "C" __global__ __launch_bounds__(WGSZ, 1)
void mlp_k(const float* __restrict__ x, const float* __restrict__ t,
           const float* __restrict__ W1, const float* __restrict__ b1,
           const float* __restrict__ W2, const float* __restrict__ b2,
           const float* __restrict__ W3, const float* __restrict__ b3,
           const float* __restrict__ W4, const float* __restrict__ b4,
           const float* __restrict__ W5, const float* __restrict__ b5p,
           float* __restrict__ out)
{
  __shared__ unsigned smem[SMEM_U32];
  const int tid = threadIdx.x;

  // ---------- stage weights (once per WG) ----------
  // mid layers, 9 kk slots: kk<8: slot = pack(W[k][c], W[k+1][c]),
  // k=16kk+8(lane>>5)+2j2, c=32mi+(lane&31); kk==8: row128 = bias[c], rows 129+ = 0.
  {
    const float* Wm[3] = {W2, W3, W4};
    const float* Bm[3] = {b2, b3, b4};
#pragma unroll
    for (int L = 0; L < 3; ++L) {
      const float* W = Wm[L];
      const float* Bv = Bm[L];
#pragma unroll 1
      for (int it = 0; it < 18; ++it) {
        int i = it*WGSZ + tid;           // 0..9215
        int lane = i & 63, j2 = (i >> 6) & 3, mi = (i >> 8) & 3, kk = i >> 10;  // kk 0..8
        int c = 32*mi + (lane & 31);
        unsigned v;
        if (kk < 8) {
          int k = 16*kk + 8*(lane >> 5) + 2*j2;
          v = pack_rn(W[k*128 + c], W[(k+1)*128 + c]);
        } else {
          v = (lane < 32 && j2 == 0) ? pack_rn(Bv[c], 0.f) : 0u;
        }
        smem[L*9216 + ((kk*4 + mi)*64 + lane)*4 + j2] = v;
      }
    }
  }
  // W1 (3x128), K padded to 16; bias b1 folded at row k=3
#pragma unroll 1
  for (int it = 0; it < 2; ++it) {
    int i = it*WGSZ + tid;
    int lane = i & 63, j2 = (i >> 6) & 3, mi = (i >> 8) & 3;
    int k = 8*(lane >> 5) + 2*j2;      // even
    int c = 32*mi + (lane & 31);
    float a = (k < 3) ? W1[k*128 + c] : 0.f;
    float b = (k+1 < 3) ? W1[(k+1)*128 + c] : ((k+1 == 3) ? b1[c] : 0.f);
    smem[W1FRAGO + (mi*64 + lane)*4 + j2] = pack_rn(a, b);
  }
  // W5 (128x2), M padded to 32 (rows >=2 are zero)
#pragma unroll 1
  for (int it = 0; it < 4; ++it) {
    int i = it*WGSZ + tid;
    int lane = i & 63, j2 = (i >> 6) & 3, kk = (i >> 8) & 7;
    int m = lane & 31;
    int k = 16*kk + 8*(lane >> 5) + 2*j2;
    float a = (m < 2) ? W5[k*2 + m]     : 0.f;
    float b = (m < 2) ? W5[(k+1)*2 + m] : 0.f;
    smem[W5FRAGO + (kk*64 + lane)*4 + j2] = pack_rn(a, b);
  }
  if (tid < 2) smem[B5O + tid] = __builtin_bit_cast(unsigned, b5p[tid]);
  __syncthreads();

  // ---------- compute: no further barriers, waves free-run ----------
  const int lane = tid & 63;
  const int wv   = tid >> 6;
  const int h5   = lane >> 5;
  const int col  = lane & 31;
  const bool lo  = lane < 32;
  const unsigned bias_w0 = h5 ? 0u : 0x00003C00u;  // B-word for kk=8: pack(1.0h, 0)
  const float b50 = reinterpret_cast<const float*>(smem + B5O)[0];
  const float b51 = reinterpret_cast<const float*>(smem + B5O)[1];
  const float2* x2 = reinterpret_cast<const float2*>(x);

#pragma unroll 1
  for (int ps = 0; ps < CHUNKS*2; ++ps) {
    const int base = ((int)blockIdx.x * CHUNKS + (ps >> 1)) * WGSZ + wv * 64 + 32*(ps & 1);
    const int s = base + col;

    float2 xa = x2[s];
    float  ta = t[s];

    // L1 B-operand: feats {x0,x1,t,1(bias)} in lanes h5==0, j<4
    half8 b1f = mkfrag(h5 ? 0u : pack_rn(xa.x, xa.y),
                       h5 ? 0u : pack_rn(ta, 1.0f), 0u, 0u);

    unsigned pkA[4][8], pkB[4][8];

    // L1 (quarter-at-a-time; bias comes through the MFMA)
#pragma unroll
    for (int mi = 0; mi < 4; ++mi) {
      f32x16 acc;
#pragma unroll
      for (int e = 0; e < 16; ++e) acc[e] = 0.f;
      half8 a = ldfrag(smem + W1FRAGO + (mi*64 + lane)*4);
      acc = __builtin_amdgcn_mfma_f32_32x32x16_f16(a, b1f, acc, 0, 0, 0);
#pragma unroll
      for (int p = 0; p < 8; ++p)
        pkA[mi][p] = pack_rtz(sw(acc[2*p]), sw(acc[2*p+1]));
      FENCE();
    }

    // L2..L4 (ping-pong pkA/pkB, static chain)
    layer_v2(pkA, pkB, smem + WFRAG0, bias_w0, lane);
    layer_v2(pkB, pkA, smem + WFRAG1, bias_w0, lane);
    layer_v2(pkA, pkB, smem + WFRAG2, bias_w0, lane);

    // L5: out^T = W5^T @ h4^T + b5 (rows 0,1 -> lanes h5==0, regs 0,1)
    f32x16 a5;
#pragma unroll
    for (int e = 0; e < 16; ++e) a5[e] = 0.f;
    a5[0] = b50; a5[1] = b51;
#pragma unroll
    for (int ks = 0; ks < 4; ++ks) {
      half8 bf0, bf1;
      build_b(pkB[ks], bf0, bf1);
      half8 a0 = ldfrag(smem + W5FRAGO + ((2*ks  )*64 + lane)*4);
      a5 = __builtin_amdgcn_mfma_f32_32x32x16_f16(a0, bf0, a5, 0, 0, 0);
      half8 a1 = ldfrag(smem + W5FRAGO + ((2*ks+1)*64 + lane)*4);
      a5 = __builtin_amdgcn_mfma_f32_32x32x16_f16(a1, bf1, a5, 0, 0, 0);
    }
    if (lo) {
      reinterpret_cast<float2*>(out)[s] = make_float2(a5[0], a5[1]);
    }
    FENCE();
  }
}

extern "C" void kernel_launch(void* const* d_in, const int* in_sizes, int n_in,
                              void* d_out, int out_size, void* d_ws, size_t ws_size,
                              hipStream_t stream) {
  (void)in_sizes; (void)n_in; (void)d_ws; (void)ws_size; (void)out_size;
  const float* x  = (const float*)d_in[0];
  const float* t  = (const float*)d_in[1];
  const float* W1 = (const float*)d_in[2];
  const float* b1 = (const float*)d_in[3];
  const float* W2 = (const float*)d_in[4];
  const float* b2 = (const float*)d_in[5];
  const float* W3 = (const float*)d_in[6];
  const float* b3 = (const float*)d_in[7];
  const float* W4 = (const float*)d_in[8];
  const float* b4 = (const float*)d_in[9];
  const float* W5 = (const float*)d_in[10];
  const float* b5 = (const float*)d_in[11];
  float* out = (float*)d_out;

  mlp_k<<<dim3(NWG), dim3(WGSZ), 0, stream>>>(x, t, W1, b1, W2, b2, W3, b3, W4, b4, W5, b5, out);
}

// Round 11
// 245.003 us; speedup vs baseline: 1.0645x; 1.0645x over previous
//
#include <hip/hip_runtime.h>

typedef _Float16 half8  __attribute__((ext_vector_type(8)));
typedef __fp16   fp16x2 __attribute__((ext_vector_type(2)));
typedef float    f32x16 __attribute__((ext_vector_type(16)));
typedef unsigned uint2v __attribute__((ext_vector_type(2)));

#define NWG     256
#define WGSZ    1024       // 16 waves/WG -> 4 waves/SIMD (r10 had 2: latency-starved)
#define NWAVES  (WGSZ/64)
#define SPW     4096       // samples per WG
#define PASSES  (SPW/(NWAVES*32))   // 8
// u32 offsets inside static LDS. Mid layers have 9 kk slots (kk=8 = bias row).
#define WFRAG0   0         // W2: 9216 u32
#define WFRAG1   9216      // W3
#define WFRAG2   18432     // W4
#define W1FRAGO  27648     // 1024 u32 (bias folded at k=3)
#define W5FRAGO  28672     // 2048 u32
#define B5O      30720     // b5: 2 f32
#define SMEM_U32 30722     // 122888 B static LDS -> 1 WG/CU

// Fence the instruction scheduler (r9: removed 1.6GB/dispatch scratch spill by
// capping load-hoisting scope; VGPR pressure must stay < 128).
#define FENCE() __builtin_amdgcn_sched_barrier(0)

__device__ __forceinline__ unsigned pack_rn(float a, float b) {
  unsigned lo = (unsigned)__builtin_bit_cast(unsigned short, (_Float16)a);
  unsigned hi = (unsigned)__builtin_bit_cast(unsigned short, (_Float16)b);
  return lo | (hi << 16);
}
__device__ __forceinline__ unsigned pack_rtz(float a, float b) {
  fp16x2 h = __builtin_amdgcn_cvt_pkrtz(a, b);
  return __builtin_bit_cast(unsigned, h);
}
// swish = v * rcp(1 + 2^(-v*log2e)) : 3 VALU + 2 trans
__device__ __forceinline__ float sw(float v) {
  float e = __builtin_amdgcn_exp2f(v * -1.44269504089f);
  return v * __builtin_amdgcn_rcpf(1.0f + e);
}
__device__ __forceinline__ half8 ldfrag(const unsigned* p) {
  uint4 u = *reinterpret_cast<const uint4*>(p);
  return __builtin_bit_cast(half8, u);
}
__device__ __forceinline__ half8 mkfrag(unsigned a, unsigned b, unsigned c, unsigned d) {
  uint4 u = make_uint4(a, b, c, d);
  return __builtin_bit_cast(half8, u);
}

__device__ __forceinline__ void pl_swap(unsigned &a, unsigned &b) {
#if __has_builtin(__builtin_amdgcn_permlane32_swap)
  uint2v r = __builtin_amdgcn_permlane32_swap(a, b, false, false);
  a = r.x; b = r.y;
#else
  asm("v_permlane32_swap_b32 %0, %1" : "+v"(a), "+v"(b));
#endif
}

// Regroup packed D-frag (source frag ks) into the two B-frags for kk=2ks, 2ks+1.
__device__ __forceinline__ void build_b(const unsigned (&p)[8], half8 &bf0, half8 &bf1) {
  unsigned a0 = p[0], a2 = p[2];
  unsigned a1 = p[1], a3 = p[3];
  unsigned a4 = p[4], a6 = p[6];
  unsigned a5 = p[5], a7 = p[7];
  pl_swap(a0, a2);
  pl_swap(a1, a3);
  pl_swap(a4, a6);
  pl_swap(a5, a7);
  bf0 = mkfrag(a0, a1, a2, a3);
  bf1 = mkfrag(a4, a5, a6, a7);
}

// One 128x128 layer for 32 samples. bf hoisted; acc[4] = 4 independent MFMA
// chains; bias applied via the kk=8 weight slot.
// Peak live: bf(32) + acc(64) + frags(16, FENCE per kk) ~ 115 < 128.
__device__ __forceinline__ void layer_v2(const unsigned (&pin)[4][8], unsigned (&pout)[4][8],
                                         const unsigned* wb, unsigned bias_w0, int lane) {
  // phase A: build all B-frags; pin dies here
  half8 bf[4][2];
#pragma unroll
  for (int ks = 0; ks < 4; ++ks) build_b(pin[ks], bf[ks][0], bf[ks][1]);
  FENCE();
  // phase B: MFMA over 8 weight kk slots + bias slot
  f32x16 acc[4];
#pragma unroll
  for (int mi = 0; mi < 4; ++mi)
#pragma unroll
    for (int e = 0; e < 16; ++e) acc[mi][e] = 0.f;
#pragma unroll
  for (int kk = 0; kk < 8; ++kk) {
#pragma unroll
    for (int mi = 0; mi < 4; ++mi) {
      half8 a = ldfrag(wb + ((kk*4 + mi)*64 + lane)*4);
      acc[mi] = __builtin_amdgcn_mfma_f32_32x32x16_f16(a, bf[kk>>1][kk&1], acc[mi], 0, 0, 0);
    }
    FENCE();
  }
  {
    half8 bb = mkfrag(bias_w0, 0u, 0u, 0u);  // B[k=128]=1 for every sample col
#pragma unroll
    for (int mi = 0; mi < 4; ++mi) {
      half8 a = ldfrag(wb + ((8*4 + mi)*64 + lane)*4);  // row128 = bias, rest 0
      acc[mi] = __builtin_amdgcn_mfma_f32_32x32x16_f16(a, bb, acc[mi], 0, 0, 0);
    }
  }
  FENCE();
  // phase C: swish + pack
#pragma unroll
  for (int mi = 0; mi < 4; ++mi)
#pragma unroll
    for (int p = 0; p < 8; ++p)
      pout[mi][p] = pack_rtz(sw(acc[mi][2*p]), sw(acc[mi][2*p+1]));
  FENCE();
}

extern "C" __global__ __launch_bounds__(WGSZ, 1)
void mlp_k(const float* __restrict__ x, const float* __restrict__ t,
           const float* __restrict__ W1, const float* __restrict__ b1,
           const float* __restrict__ W2, const float* __restrict__ b2,
           const float* __restrict__ W3, const float* __restrict__ b3,
           const float* __restrict__ W4, const float* __restrict__ b4,
           const float* __restrict__ W5, const float* __restrict__ b5p,
           float* __restrict__ out)
{
  __shared__ unsigned smem[SMEM_U32];
  const int tid = threadIdx.x;

  // ---------- stage weights (once per WG) ----------
  // mid layers, 9 kk slots: kk<8: slot = pack(W[k][c], W[k+1][c]),
  // k=16kk+8(lane>>5)+2j2, c=32mi+(lane&31); kk==8: row128 = bias[c], rows 129+ = 0.
  {
    const float* Wm[3] = {W2, W3, W4};
    const float* Bm[3] = {b2, b3, b4};
#pragma unroll
    for (int L = 0; L < 3; ++L) {
      const float* W = Wm[L];
      const float* Bv = Bm[L];
#pragma unroll 1
      for (int it = 0; it < 9; ++it) {
        int i = it*WGSZ + tid;           // 0..9215
        int lane = i & 63, j2 = (i >> 6) & 3, mi = (i >> 8) & 3, kk = i >> 10;  // kk 0..8
        int c = 32*mi + (lane & 31);
        unsigned v;
        if (kk < 8) {
          int k = 16*kk + 8*(lane >> 5) + 2*j2;
          v = pack_rn(W[k*128 + c], W[(k+1)*128 + c]);
        } else {
          v = (lane < 32 && j2 == 0) ? pack_rn(Bv[c], 0.f) : 0u;
        }
        smem[L*9216 + ((kk*4 + mi)*64 + lane)*4 + j2] = v;
      }
    }
  }
  // W1 (3x128), K padded to 16; bias b1 folded at row k=3
  if (tid < 1024) {
    int i = tid;
    int lane = i & 63, j2 = (i >> 6) & 3, mi = (i >> 8) & 3;
    int k = 8*(lane >> 5) + 2*j2;      // even
    int c = 32*mi + (lane & 31);
    float a = (k < 3) ? W1[k*128 + c] : 0.f;
    float b = (k+1 < 3) ? W1[(k+1)*128 + c] : ((k+1 == 3) ? b1[c] : 0.f);
    smem[W1FRAGO + (mi*64 + lane)*4 + j2] = pack_rn(a, b);
  }
  // W5 (128x2), M padded to 32 (rows >=2 are zero)
#pragma unroll 1
  for (int it = 0; it < 2; ++it) {
    int i = it*WGSZ + tid;
    int lane = i & 63, j2 = (i >> 6) & 3, kk = (i >> 8) & 7;
    int m = lane & 31;
    int k = 16*kk + 8*(lane >> 5) + 2*j2;
    float a = (m < 2) ? W5[k*2 + m]     : 0.f;
    float b = (m < 2) ? W5[(k+1)*2 + m] : 0.f;
    smem[W5FRAGO + (kk*64 + lane)*4 + j2] = pack_rn(a, b);
  }
  if (tid < 2) smem[B5O + tid] = __builtin_bit_cast(unsigned, b5p[tid]);
  __syncthreads();

  // ---------- compute: no further barriers, waves free-run ----------
  const int lane = tid & 63;
  const int wv   = tid >> 6;
  const int h5   = lane >> 5;
  const int col  = lane & 31;
  const bool lo  = lane < 32;
  const unsigned bias_w0 = h5 ? 0u : 0x00003C00u;  // B-word for kk=8: pack(1.0h, 0)
  const float b50 = reinterpret_cast<const float*>(smem + B5O)[0];
  const float b51 = reinterpret_cast<const float*>(smem + B5O)[1];
  const float2* x2 = reinterpret_cast<const float2*>(x);

#pragma unroll 1
  for (int ps = 0; ps < PASSES; ++ps) {
    const int base = (int)blockIdx.x * SPW + (ps * NWAVES + wv) * 32;
    const int s = base + col;

    float2 xa = x2[s];
    float  ta = t[s];

    // L1 B-operand: feats {x0,x1,t,1(bias)} in lanes h5==0, j<4
    half8 b1f = mkfrag(h5 ? 0u : pack_rn(xa.x, xa.y),
                       h5 ? 0u : pack_rn(ta, 1.0f), 0u, 0u);

    unsigned pkA[4][8], pkB[4][8];

    // L1 (quarter-at-a-time; bias comes through the MFMA)
#pragma unroll
    for (int mi = 0; mi < 4; ++mi) {
      f32x16 acc;
#pragma unroll
      for (int e = 0; e < 16; ++e) acc[e] = 0.f;
      half8 a = ldfrag(smem + W1FRAGO + (mi*64 + lane)*4);
      acc = __builtin_amdgcn_mfma_f32_32x32x16_f16(a, b1f, acc, 0, 0, 0);
#pragma unroll
      for (int p = 0; p < 8; ++p)
        pkA[mi][p] = pack_rtz(sw(acc[2*p]), sw(acc[2*p+1]));
      FENCE();
    }

    // L2..L4 (ping-pong pkA/pkB, static chain)
    layer_v2(pkA, pkB, smem + WFRAG0, bias_w0, lane);
    layer_v2(pkB, pkA, smem + WFRAG1, bias_w0, lane);
    layer_v2(pkA, pkB, smem + WFRAG2, bias_w0, lane);

    // L5: out^T = W5^T @ h4^T + b5 (rows 0,1 -> lanes h5==0, regs 0,1)
    f32x16 a5;
#pragma unroll
    for (int e = 0; e < 16; ++e) a5[e] = 0.f;
    a5[0] = b50; a5[1] = b51;
#pragma unroll
    for (int ks = 0; ks < 4; ++ks) {
      half8 bf0, bf1;
      build_b(pkB[ks], bf0, bf1);
      half8 a0 = ldfrag(smem + W5FRAGO + ((2*ks  )*64 + lane)*4);
      a5 = __builtin_amdgcn_mfma_f32_32x32x16_f16(a0, bf0, a5, 0, 0, 0);
      half8 a1 = ldfrag(smem + W5FRAGO + ((2*ks+1)*64 + lane)*4);
      a5 = __builtin_amdgcn_mfma_f32_32x32x16_f16(a1, bf1, a5, 0, 0, 0);
    }
    if (lo) {
      reinterpret_cast<float2*>(out)[s] = make_float2(a5[0], a5[1]);
    }
    FENCE();
  }
}

extern "C" void kernel_launch(void* const* d_in, const int* in_sizes, int n_in,
                              void* d_out, int out_size, void* d_ws, size_t ws_size,
                              hipStream_t stream) {
  (void)in_sizes; (void)n_in; (void)d_ws; (void)ws_size; (void)out_size;
  const float* x  = (const float*)d_in[0];
  const float* t  = (const float*)d_in[1];
  const float* W1 = (const float*)d_in[2];
  const float* b1 = (const float*)d_in[3];
  const float* W2 = (const float*)d_in[4];
  const float* b2 = (const float*)d_in[5];
  const float* W3 = (const float*)d_in[6];
  const float* b3 = (const float*)d_in[7];
  const float* W4 = (const float*)d_in[8];
  const float* b4 = (const float*)d_in[9];
  const float* W5 = (const float*)d_in[10];
  const float* b5 = (const float*)d_in[11];
  float* out = (float*)d_out;

  mlp_k<<<dim3(NWG), dim3(WGSZ), 0, stream>>>(x, t, W1, b1, W2, b2, W3, b3, W4, b4, W5, b5, out);
}